// Round 9
// baseline (256.407 us; speedup 1.0000x reference)
//
#include <hip/hip_runtime.h>
#include <math.h>

// VQ-VAE EMA vector quantizer for MI355X (gfx950).
// Argmin bit-replicates the numpy-f32 reference: dists = (sum(x*x) - (2x)@emb.T) + sum(e*e),
// numpy pairwise row-sums, BLAS sequential-FMA dot, first-occurrence argmin.
// dw/counts via counting-sort segmented reduction (no f32 global atomics).
// Round 9: quarter-K k_scores — 256 threads / 64 rows, wave w scores codes [w*128, w*128+128)
// for all 64 rows; xs[64][64] = 16KB -> ~19.6KB LDS/block -> 8 blocks/CU = 32 waves/CU
// (max occupancy) to hide scalar-load latency. Partial argmins merged in quarter order
// (strict < keeps first occurrence).
#define NROWS 131072          // 32*4096
#define DIM 64
#define NCODE 512
#define BROWS 64              // rows per k_scores block

// d_out float offsets (outputs concatenated flat, all float32-viewed)
#define OUT_ZQ    0
#define OUT_LOSS  8388608
#define OUT_CODES 8388609
#define OUT_ECS   8519681
#define OUT_EMAW  8520193
#define OUT_EMB   8552961

// workspace byte offsets
#define WS_LOSS    0         // double
#define WS_N       8         // float
#define WS_COUNTS  16        // int[512]
#define WS_OFFSETS 2064      // int[512]
#define WS_CURSOR  4112      // int[512]
#define WS_CSUM    6160      // float[512]
#define WS_CODESI  8208      // int[131072]; retired after k_scatter, reused as dw4
#define WS_DW4     8208      // float[4*512*64] = 512 KB, aliases codes_i (safe: k_dw after k_scatter)
#define WS_BUCKET  532496    // int[131072]
#define WS_BYTES   1056784
#define WS_ZERO_BYTES 2064   // loss + n + counts

// reference scalar constants
#define DECAY_C ((float)0.9)
#define OMD_C   ((float)(1.0 - 0.9))
#define EPS_C   ((float)1e-5)

// repetition macros (all indices literal constants)
#define R4(M, b)  M(b) M((b) + 1) M((b) + 2) M((b) + 3)
#define R16(M, b) R4(M, b) R4(M, (b) + 4) R4(M, (b) + 8) R4(M, (b) + 12)

// numpy pairwise sum (scalar unroll-8 path, n=64) of v[d]*v[d], f32, no contraction.
__device__ __forceinline__ float np_pairwise64_sq(const float* v) {
    float r[8];
#pragma unroll
    for (int j = 0; j < 8; ++j) r[j] = __fmul_rn(v[j], v[j]);
#pragma unroll
    for (int b = 1; b < 8; ++b) {
#pragma unroll
        for (int j = 0; j < 8; ++j)
            r[j] = __fadd_rn(r[j], __fmul_rn(v[8 * b + j], v[8 * b + j]));
    }
    return __fadd_rn(__fadd_rn(__fadd_rn(r[0], r[1]), __fadd_rn(r[2], r[3])),
                     __fadd_rn(__fadd_rn(r[4], r[5]), __fadd_rn(r[6], r[7])));
}

// ---- csum[k] = np.sum(emb[k]*emb[k]) with numpy pairwise bits ----
__global__ void k_csum(const float* __restrict__ emb, float* __restrict__ csum) {
    int k = blockIdx.x * blockDim.x + threadIdx.x;
    if (k >= NCODE) return;
    float e[DIM];
#pragma unroll
    for (int d = 0; d < DIM; d += 4) {
        float4 v = *reinterpret_cast<const float4*>(emb + (size_t)k * DIM + d);
        e[d] = v.x; e[d + 1] = v.y; e[d + 2] = v.z; e[d + 3] = v.w;
    }
    csum[k] = np_pairwise64_sq(e);
}

// ---- fused: quarter-K argmin + codes + z_q + loss + LDS histogram ----
__global__ __launch_bounds__(256) void k_scores(
        const float* __restrict__ ze, const float* __restrict__ emb,
        const float* __restrict__ csum, float* __restrict__ out,
        int* __restrict__ codes_i, int* __restrict__ counts,
        double* __restrict__ lossAcc) {
    __shared__ float xs[DIM][BROWS];  // xs[d][c] = 2*x_d for row c of this block
    __shared__ float ms[3][BROWS];    // quarters 1..3 partial min
    __shared__ int   ii[3][BROWS];    // quarters 1..3 partial argmin
    __shared__ int h[NCODE];
    __shared__ double ls[4];
    int t = threadIdx.x;
    int c = t & 63;                   // row-in-block / xs column (= lane)
    int q = t >> 6;                   // quarter = wave id (wave-uniform)
    for (int i = t; i < NCODE; i += 256) h[i] = 0;

    int row = blockIdx.x * BROWS + c;
    const float* x = ze + (size_t)row * DIM;

    // All 4 quarters load the row (same addresses -> L1 hits) and write xs
    // (identical bits -> benign race; each thread reads only its own column).
    float r0, r1, r2, r3, r4, r5, r6, r7;
    {   // d = 0..7: initialize numpy pairwise partials
        float4 va = *reinterpret_cast<const float4*>(x + 0);
        float4 vb = *reinterpret_cast<const float4*>(x + 4);
        float d0 = __fadd_rn(va.x, va.x), d1 = __fadd_rn(va.y, va.y);
        float d2 = __fadd_rn(va.z, va.z), d3 = __fadd_rn(va.w, va.w);
        float d4 = __fadd_rn(vb.x, vb.x), d5 = __fadd_rn(vb.y, vb.y);
        float d6 = __fadd_rn(vb.z, vb.z), d7 = __fadd_rn(vb.w, vb.w);
        xs[0][c] = d0; xs[1][c] = d1; xs[2][c] = d2; xs[3][c] = d3;
        xs[4][c] = d4; xs[5][c] = d5; xs[6][c] = d6; xs[7][c] = d7;
        r0 = __fmul_rn(d0, d0); r1 = __fmul_rn(d1, d1);
        r2 = __fmul_rn(d2, d2); r3 = __fmul_rn(d3, d3);
        r4 = __fmul_rn(d4, d4); r5 = __fmul_rn(d5, d5);
        r6 = __fmul_rn(d6, d6); r7 = __fmul_rn(d7, d7);
    }
#define LD8(b) { \
        float4 va = *reinterpret_cast<const float4*>(x + 8 * (b)); \
        float4 vb = *reinterpret_cast<const float4*>(x + 8 * (b) + 4); \
        float d0 = __fadd_rn(va.x, va.x), d1 = __fadd_rn(va.y, va.y); \
        float d2 = __fadd_rn(va.z, va.z), d3 = __fadd_rn(va.w, va.w); \
        float d4 = __fadd_rn(vb.x, vb.x), d5 = __fadd_rn(vb.y, vb.y); \
        float d6 = __fadd_rn(vb.z, vb.z), d7 = __fadd_rn(vb.w, vb.w); \
        xs[8 * (b) + 0][c] = d0; xs[8 * (b) + 1][c] = d1; \
        xs[8 * (b) + 2][c] = d2; xs[8 * (b) + 3][c] = d3; \
        xs[8 * (b) + 4][c] = d4; xs[8 * (b) + 5][c] = d5; \
        xs[8 * (b) + 6][c] = d6; xs[8 * (b) + 7][c] = d7; \
        r0 = __fadd_rn(r0, __fmul_rn(d0, d0)); r1 = __fadd_rn(r1, __fmul_rn(d1, d1)); \
        r2 = __fadd_rn(r2, __fmul_rn(d2, d2)); r3 = __fadd_rn(r3, __fmul_rn(d3, d3)); \
        r4 = __fadd_rn(r4, __fmul_rn(d4, d4)); r5 = __fadd_rn(r5, __fmul_rn(d5, d5)); \
        r6 = __fadd_rn(r6, __fmul_rn(d6, d6)); r7 = __fadd_rn(r7, __fmul_rn(d7, d7)); }
    LD8(1) LD8(2) LD8(3) LD8(4) LD8(5) LD8(6) LD8(7)
    // A = sum(x^2) = 0.25 * sum((2x)^2), numpy pairwise combine, bit-exact
    float A = __fmul_rn(0.25f,
        __fadd_rn(__fadd_rn(__fadd_rn(r0, r1), __fadd_rn(r2, r3)),
                  __fadd_rn(__fadd_rn(r4, r5), __fadd_rn(r6, r7))));

    // wave-uniform code base; readfirstlane keeps emb loads on the s_load path
    int kbase = __builtin_amdgcn_readfirstlane(q << 7);

    float m1 = 3.4e38f;
    int i1 = kbase;
#define FMAD(dd) { const float xv = xs[dd][c]; \
        a0 = __builtin_fmaf(xv, e[(dd)      ], a0); \
        a1 = __builtin_fmaf(xv, e[(dd) +  64], a1); \
        a2 = __builtin_fmaf(xv, e[(dd) + 128], a2); \
        a3 = __builtin_fmaf(xv, e[(dd) + 192], a3); \
        a4 = __builtin_fmaf(xv, e[(dd) + 256], a4); \
        a5 = __builtin_fmaf(xv, e[(dd) + 320], a5); \
        a6 = __builtin_fmaf(xv, e[(dd) + 384], a6); \
        a7 = __builtin_fmaf(xv, e[(dd) + 448], a7); }
    for (int kk = 0; kk < NCODE / 4; kk += 8) {
        int k = kbase + kk;
        const float* e = emb + (size_t)k * DIM;     // wave-uniform -> scalar loads
        float a0 = 0.f, a1 = 0.f, a2 = 0.f, a3 = 0.f;
        float a4 = 0.f, a5 = 0.f, a6 = 0.f, a7 = 0.f;
        R16(FMAD, 0) R16(FMAD, 16) R16(FMAD, 32) R16(FMAD, 48)   // d ascending, BLAS chain
        float t0 = __fadd_rn(__fsub_rn(A, a0), csum[k + 0]);
        float t1 = __fadd_rn(__fsub_rn(A, a1), csum[k + 1]);
        float t2 = __fadd_rn(__fsub_rn(A, a2), csum[k + 2]);
        float t3 = __fadd_rn(__fsub_rn(A, a3), csum[k + 3]);
        float t4 = __fadd_rn(__fsub_rn(A, a4), csum[k + 4]);
        float t5 = __fadd_rn(__fsub_rn(A, a5), csum[k + 5]);
        float t6 = __fadd_rn(__fsub_rn(A, a6), csum[k + 6]);
        float t7 = __fadd_rn(__fsub_rn(A, a7), csum[k + 7]);
        if (t0 < m1) { m1 = t0; i1 = k; }           // strict < keeps first occurrence
        if (t1 < m1) { m1 = t1; i1 = k + 1; }
        if (t2 < m1) { m1 = t2; i1 = k + 2; }
        if (t3 < m1) { m1 = t3; i1 = k + 3; }
        if (t4 < m1) { m1 = t4; i1 = k + 4; }
        if (t5 < m1) { m1 = t5; i1 = k + 5; }
        if (t6 < m1) { m1 = t6; i1 = k + 6; }
        if (t7 < m1) { m1 = t7; i1 = k + 7; }
    }
    if (q) { ms[q - 1][c] = m1; ii[q - 1][c] = i1; }
    __syncthreads();                                // partials + h init visible

    double lsum = 0.0;
    if (q == 0) {
        // merge quarters in ascending order; strict < -> lowest index on ties
        float mh0 = ms[0][c]; int ih0 = ii[0][c];
        float mh1 = ms[1][c]; int ih1 = ii[1][c];
        float mh2 = ms[2][c]; int ih2 = ii[2][c];
        if (mh0 < m1) { m1 = mh0; i1 = ih0; }
        if (mh1 < m1) { m1 = mh1; i1 = ih1; }
        if (mh2 < m1) { m1 = mh2; i1 = ih2; }
        out[OUT_CODES + row] = (float)i1;
        codes_i[row] = i1;
        atomicAdd(&h[i1], 1);                       // LDS atomic

        // z_q = x + (e - x), loss; x recovered exactly as 0.5*(2x)
        const float* e1 = emb + (size_t)i1 * DIM;
        float* zq = out + OUT_ZQ + (size_t)row * DIM;
#define ZQ4(qq) { \
        float4 ev = *reinterpret_cast<const float4*>(e1 + 4 * (qq)); \
        float xa = __fmul_rn(0.5f, xs[4 * (qq) + 0][c]); \
        float xb = __fmul_rn(0.5f, xs[4 * (qq) + 1][c]); \
        float xc = __fmul_rn(0.5f, xs[4 * (qq) + 2][c]); \
        float xd = __fmul_rn(0.5f, xs[4 * (qq) + 3][c]); \
        float ta = __fsub_rn(ev.x, xa); \
        float tb = __fsub_rn(ev.y, xb); \
        float tc = __fsub_rn(ev.z, xc); \
        float td = __fsub_rn(ev.w, xd); \
        float4 o; \
        o.x = __fadd_rn(xa, ta); \
        o.y = __fadd_rn(xb, tb); \
        o.z = __fadd_rn(xc, tc); \
        o.w = __fadd_rn(xd, td); \
        *reinterpret_cast<float4*>(zq + 4 * (qq)) = o; \
        lsum += (double)ta * ta + (double)tb * tb + (double)tc * tc + (double)td * td; }
        R16(ZQ4, 0)
    }

    for (int off = 32; off; off >>= 1) lsum += __shfl_down(lsum, off);
    if ((t & 63) == 0) ls[q] = lsum;                // quarters 1-3 contribute 0
    __syncthreads();                                // also orders LDS histogram
    if (t == 0) atomicAdd(lossAcc, (ls[0] + ls[1]) + (ls[2] + ls[3]));
    for (int k = t; k < NCODE; k += 256) {
        int cc = h[k];
        if (cc) atomicAdd(&counts[k], cc);          // int global atomic, aggregated
    }
}

// ---- one block: exclusive scan of counts -> offsets/cursor; new_ecs + n ----
__global__ __launch_bounds__(512) void k_scan(
        const int* __restrict__ counts, int* __restrict__ offsets, int* __restrict__ cursor,
        const float* __restrict__ ecs_in, float* __restrict__ out, float* __restrict__ n_out) {
    __shared__ int sa[NCODE], sb[NCODE];
    __shared__ float red[NCODE];
    int k = threadIdx.x;
    int c = counts[k];
    sa[k] = c;
    float v = __fadd_rn(__fmul_rn(ecs_in[k], DECAY_C), __fmul_rn((float)c, OMD_C));
    out[OUT_ECS + k] = v;
    red[k] = v;
    __syncthreads();
    int* src = sa;
    int* dst = sb;
    for (int off = 1; off < NCODE; off <<= 1) {
        dst[k] = (k >= off) ? src[k - off] + src[k] : src[k];
        __syncthreads();
        int* tp = src; src = dst; dst = tp;
    }
    offsets[k] = src[k] - c;
    cursor[k]  = src[k] - c;
    for (int s = NCODE / 2; s > 0; s >>= 1) {
        if (k < s) red[k] += red[k + s];
        __syncthreads();
    }
    if (k == 0) n_out[0] = red[0];
}

// ---- scatter rows into code buckets ----
__global__ __launch_bounds__(256) void k_scatter(
        const int* __restrict__ codes_i, int* __restrict__ cursor, int* __restrict__ bucket) {
    int row = blockIdx.x * 256 + threadIdx.x;
    int c = codes_i[row];
    int pos = atomicAdd(&cursor[c], 1);
    bucket[pos] = row;
}

// ---- per-code segmented sum, 4 blocks per code -> dw4 partials (no atomics) ----
__global__ __launch_bounds__(256) void k_dw(
        const float* __restrict__ ze, const int* __restrict__ bucket,
        const int* __restrict__ offsets, const int* __restrict__ counts,
        float* __restrict__ dw4) {
    __shared__ float p[4][DIM];
    int k = blockIdx.x >> 2;
    int q = blockIdx.x & 3;         // quarter of this bucket
    int w = threadIdx.x >> 6;       // wave 0..3
    int d = threadIdx.x & 63;
    int s = offsets[k];
    int n = counts[k];
    float acc0 = 0.f, acc1 = 0.f;
    int i = q + 4 * w;              // residue q mod 4, wave-strided
    for (; i + 16 < n; i += 32) {   // 2 gathers in flight per wave
        int ra = bucket[s + i];
        int rb = bucket[s + i + 16];
        acc0 += ze[(size_t)ra * DIM + d];
        acc1 += ze[(size_t)rb * DIM + d];
    }
    if (i < n) acc0 += ze[(size_t)bucket[s + i] * DIM + d];
    p[w][d] = acc0 + acc1;
    __syncthreads();
    if (w == 0) dw4[((size_t)q * NCODE + k) * DIM + d] = (p[0][d] + p[1][d]) + (p[2][d] + p[3][d]);
}

// ---- new_ema_w, new_emb, loss ----
__global__ __launch_bounds__(256) void k_final(
        const float* __restrict__ ema_w, const float* __restrict__ dw4,
        const float* __restrict__ n_ptr, const double* __restrict__ lossAcc,
        float* __restrict__ out) {
    int i = blockIdx.x * blockDim.x + threadIdx.x;
    if (i >= NCODE * DIM) return;
    int k = i >> 6;
    float dsum = __fadd_rn(__fadd_rn(dw4[i], dw4[i + NCODE * DIM]),
                           __fadd_rn(dw4[i + 2 * NCODE * DIM], dw4[i + 3 * NCODE * DIM]));
    float w = __fadd_rn(__fmul_rn(ema_w[i], DECAY_C), __fmul_rn(dsum, OMD_C));
    out[OUT_EMAW + i] = w;
    float n = n_ptr[0];
    float necs = out[OUT_ECS + k];
    float cs = (necs + EPS_C) / (n + (float)NCODE * EPS_C) * n;
    out[OUT_EMB + i] = w / (cs + EPS_C);
    if (i == 0) out[OUT_LOSS] = (float)(0.1 * (lossAcc[0] / (double)((size_t)NROWS * DIM)));
}

extern "C" void kernel_launch(void* const* d_in, const int* in_sizes, int n_in,
                              void* d_out, int out_size, void* d_ws, size_t ws_size,
                              hipStream_t stream) {
    const float* ze   = (const float*)d_in[0];
    const float* emb  = (const float*)d_in[1];
    const float* ecs  = (const float*)d_in[2];
    const float* emaw = (const float*)d_in[3];
    float* out = (float*)d_out;
    char* ws = (char*)d_ws;
    double* lossAcc = (double*)(ws + WS_LOSS);
    float*  n_out   = (float*)(ws + WS_N);
    int*    counts  = (int*)(ws + WS_COUNTS);
    int*    offsets = (int*)(ws + WS_OFFSETS);
    int*    cursor  = (int*)(ws + WS_CURSOR);
    float*  csum    = (float*)(ws + WS_CSUM);
    int*    codes_i = (int*)(ws + WS_CODESI);
    float*  dw4     = (float*)(ws + WS_DW4);     // aliases codes_i (k_dw after k_scatter)
    int*    bucket  = (int*)(ws + WS_BUCKET);

    hipMemsetAsync(d_ws, 0, WS_ZERO_BYTES, stream);
    hipLaunchKernelGGL(k_csum, dim3(2), dim3(256), 0, stream, emb, csum);
    hipLaunchKernelGGL(k_scores, dim3(NROWS / BROWS), dim3(256), 0, stream,
                       ze, emb, csum, out, codes_i, counts, lossAcc);
    hipLaunchKernelGGL(k_scan, dim3(1), dim3(512), 0, stream,
                       counts, offsets, cursor, ecs, out, n_out);
    hipLaunchKernelGGL(k_scatter, dim3(NROWS / 256), dim3(256), 0, stream,
                       codes_i, cursor, bucket);
    hipLaunchKernelGGL(k_dw, dim3(NCODE * 4), dim3(256), 0, stream,
                       ze, bucket, offsets, counts, dw4);
    hipLaunchKernelGGL(k_final, dim3(NCODE * DIM / 256), dim3(256), 0, stream,
                       emaw, dw4, n_out, lossAcc, out);
}

// Round 10
// 225.922 us; speedup vs baseline: 1.1349x; 1.1349x over previous
//
#include <hip/hip_runtime.h>
#include <math.h>

// VQ-VAE EMA vector quantizer for MI355X (gfx950).
// Round 10: bf16-split MFMA pre-pass (hi*hi + hi*lo + lo*hi) computes approximate
// scores s~ = csum - 2*x.e on the matrix pipe; rows with top-2 margin < 6e-5 are
// re-scored with the verified bit-exact numpy-f32 chain (rescue). All other rows'
// argmin provably matches np (error bound ~1.5e-5/score incl. np's own fl quantization).
// dw/counts via counting-sort segmented reduction (no f32 global atomics).
#define NROWS 131072          // 32*4096
#define DIM 64
#define NCODE 512
#define FLAG_CAP 32768
#define THR 6e-5f

// d_out float offsets
#define OUT_ZQ    0
#define OUT_LOSS  8388608
#define OUT_CODES 8388609
#define OUT_ECS   8519681
#define OUT_EMAW  8520193
#define OUT_EMB   8552961

// workspace byte offsets (total = 1187856, same footprint as prior passing rounds)
#define WS_LOSS    0         // double
#define WS_N       8         // float
#define WS_FLAGC   12        // int
#define WS_COUNTS  16        // int[512]
#define WS_OFFSETS 2064      // int[512]
#define WS_CURSOR  4112      // int[512]
#define WS_CSUM    6160      // float[512]
#define WS_EHI     8208      // ushort[512*64]
#define WS_ELO     73744     // ushort[512*64]
#define WS_CODESI  139280    // int[131072]; dead after k_scatter -> reused as dw4
#define WS_DW4     139280    // float[4*512*64]
#define WS_BUCKET  663568    // int[131072]; before k_scatter reused as flagR
#define WS_FLAGR   663568
#define WS_BYTES   1187856
#define WS_ZERO_BYTES 2064   // loss + n + flagC + counts

#define DECAY_C ((float)0.9)
#define OMD_C   ((float)(1.0 - 0.9))
#define EPS_C   ((float)1e-5)

typedef float f32x4 __attribute__((ext_vector_type(4)));
typedef short short8v __attribute__((ext_vector_type(8)));

__device__ __forceinline__ unsigned short bf16_rne_bits(float f) {
    unsigned int u = __float_as_uint(f);
    unsigned int r = u + 0x7fffu + ((u >> 16) & 1u);
    return (unsigned short)(r >> 16);
}

// numpy pairwise sum (scalar unroll-8 path, n=64) of v[d]*v[d], f32, no contraction.
__device__ __forceinline__ float np_pairwise64_sq(const float* v) {
    float r[8];
#pragma unroll
    for (int j = 0; j < 8; ++j) r[j] = __fmul_rn(v[j], v[j]);
#pragma unroll
    for (int b = 1; b < 8; ++b) {
#pragma unroll
        for (int j = 0; j < 8; ++j)
            r[j] = __fadd_rn(r[j], __fmul_rn(v[8 * b + j], v[8 * b + j]));
    }
    return __fadd_rn(__fadd_rn(__fadd_rn(r[0], r[1]), __fadd_rn(r[2], r[3])),
                     __fadd_rn(__fadd_rn(r[4], r[5]), __fadd_rn(r[6], r[7])));
}

// ---- csum[k] = np.sum(emb[k]*emb[k]) with numpy pairwise bits ----
__global__ void k_csum(const float* __restrict__ emb, float* __restrict__ csum) {
    int k = blockIdx.x * blockDim.x + threadIdx.x;
    if (k >= NCODE) return;
    float e[DIM];
#pragma unroll
    for (int d = 0; d < DIM; d += 4) {
        float4 v = *reinterpret_cast<const float4*>(emb + (size_t)k * DIM + d);
        e[d] = v.x; e[d + 1] = v.y; e[d + 2] = v.z; e[d + 3] = v.w;
    }
    csum[k] = np_pairwise64_sq(e);
}

// ---- split emb into bf16 hi/lo planes ----
__global__ __launch_bounds__(256) void k_split(
        const float* __restrict__ emb, unsigned short* __restrict__ ehi,
        unsigned short* __restrict__ elo) {
    int i = blockIdx.x * 256 + threadIdx.x;
    if (i >= NCODE * DIM) return;
    float v = emb[i];
    unsigned short h = bf16_rne_bits(v);
    float hf = __uint_as_float((unsigned int)h << 16);
    ehi[i] = h;
    elo[i] = bf16_rne_bits(v - hf);
}

// ---- MFMA scores: per wave 32 rows x 512 codes; top-2 margin -> flag list ----
#define CVTE(H, L, j, val) { \
    unsigned int ub = __float_as_uint(val); \
    unsigned int rr = ub + 0x7fffu + ((ub >> 16) & 1u); \
    unsigned short hb = (unsigned short)(rr >> 16); \
    float hf2 = __uint_as_float(((unsigned int)hb) << 16); \
    float lof = (val) - hf2; \
    unsigned int ul = __float_as_uint(lof); \
    unsigned int rl = ul + 0x7fffu + ((ul >> 16) & 1u); \
    H[j] = (short)hb; L[j] = (short)(rl >> 16); }

__global__ __launch_bounds__(256, 1) void k_mfma(
        const float* __restrict__ ze, const unsigned short* __restrict__ ehi,
        const unsigned short* __restrict__ elo, const float* __restrict__ csum,
        float* __restrict__ out, int* __restrict__ codes_i,
        int* __restrict__ flagC, int* __restrict__ flagR) {
    __shared__ float cs[NCODE];
    for (int i = threadIdx.x; i < NCODE; i += 256) cs[i] = csum[i];
    __syncthreads();
    int wid = threadIdx.x >> 6;
    int lane = threadIdx.x & 63;
    int r16 = lane & 15;
    int kg = lane >> 4;                 // k-group 0..3 (8 k-elements each)
    int rowbase = blockIdx.x * 128 + wid * 32;

    // A-fragments: [row-tile][k-half], hi and lo planes
    short8v ahi[2][2], alo[2][2];
#define LOADA(rt, hf) { \
        const float4* ap = reinterpret_cast<const float4*>( \
            ze + (size_t)(rowbase + (rt) * 16 + r16) * DIM + (hf) * 32 + 8 * kg); \
        float4 u = ap[0], w = ap[1]; \
        CVTE(ahi[rt][hf], alo[rt][hf], 0, u.x) CVTE(ahi[rt][hf], alo[rt][hf], 1, u.y) \
        CVTE(ahi[rt][hf], alo[rt][hf], 2, u.z) CVTE(ahi[rt][hf], alo[rt][hf], 3, u.w) \
        CVTE(ahi[rt][hf], alo[rt][hf], 4, w.x) CVTE(ahi[rt][hf], alo[rt][hf], 5, w.y) \
        CVTE(ahi[rt][hf], alo[rt][hf], 6, w.z) CVTE(ahi[rt][hf], alo[rt][hf], 7, w.w) }
    LOADA(0, 0) LOADA(0, 1) LOADA(1, 0) LOADA(1, 1)

    float m1v[2][4], m2v[2][4];
    int i1v[2][4];
#pragma unroll
    for (int rt = 0; rt < 2; ++rt)
#pragma unroll
        for (int j = 0; j < 4; ++j) { m1v[rt][j] = 3.4e38f; m2v[rt][j] = 3.4e38f; i1v[rt][j] = 0; }

#define UPD(C, rt, reg) { \
        float s = __builtin_fmaf(-2.f, C[reg], csv); \
        if (s < m1v[rt][reg]) { m2v[rt][reg] = m1v[rt][reg]; m1v[rt][reg] = s; i1v[rt][reg] = codeIdx; } \
        else if (s < m2v[rt][reg]) { m2v[rt][reg] = s; } }

    for (int t = 0; t < 32; ++t) {
        const short8v* bh = reinterpret_cast<const short8v*>(
            ehi + (size_t)(t * 16 + r16) * DIM + 8 * kg);
        const short8v* bl = reinterpret_cast<const short8v*>(
            elo + (size_t)(t * 16 + r16) * DIM + 8 * kg);
        short8v bh0 = bh[0], bh1 = bh[4];      // k-half 0 (d 0..31), k-half 1 (d 32..63)
        short8v bl0 = bl[0], bl1 = bl[4];
        f32x4 c0 = {0.f, 0.f, 0.f, 0.f};
        f32x4 c1 = {0.f, 0.f, 0.f, 0.f};
        c0 = __builtin_amdgcn_mfma_f32_16x16x32_bf16(ahi[0][0], bh0, c0, 0, 0, 0);
        c0 = __builtin_amdgcn_mfma_f32_16x16x32_bf16(ahi[0][1], bh1, c0, 0, 0, 0);
        c0 = __builtin_amdgcn_mfma_f32_16x16x32_bf16(alo[0][0], bh0, c0, 0, 0, 0);
        c0 = __builtin_amdgcn_mfma_f32_16x16x32_bf16(alo[0][1], bh1, c0, 0, 0, 0);
        c0 = __builtin_amdgcn_mfma_f32_16x16x32_bf16(ahi[0][0], bl0, c0, 0, 0, 0);
        c0 = __builtin_amdgcn_mfma_f32_16x16x32_bf16(ahi[0][1], bl1, c0, 0, 0, 0);
        c1 = __builtin_amdgcn_mfma_f32_16x16x32_bf16(ahi[1][0], bh0, c1, 0, 0, 0);
        c1 = __builtin_amdgcn_mfma_f32_16x16x32_bf16(ahi[1][1], bh1, c1, 0, 0, 0);
        c1 = __builtin_amdgcn_mfma_f32_16x16x32_bf16(alo[1][0], bh0, c1, 0, 0, 0);
        c1 = __builtin_amdgcn_mfma_f32_16x16x32_bf16(alo[1][1], bh1, c1, 0, 0, 0);
        c1 = __builtin_amdgcn_mfma_f32_16x16x32_bf16(ahi[1][0], bl0, c1, 0, 0, 0);
        c1 = __builtin_amdgcn_mfma_f32_16x16x32_bf16(ahi[1][1], bl1, c1, 0, 0, 0);
        float csv = cs[t * 16 + r16];
        int codeIdx = t * 16 + r16;
        UPD(c0, 0, 0) UPD(c0, 0, 1) UPD(c0, 0, 2) UPD(c0, 0, 3)
        UPD(c1, 1, 0) UPD(c1, 1, 1) UPD(c1, 1, 2) UPD(c1, 1, 3)
    }

    // reduce across the 16 lanes sharing a row (masks 1,2,4,8 stay in-group)
#define RED(rt, reg, mask) { \
        float om1 = __shfl_xor(m1v[rt][reg], mask); \
        int   oi  = __shfl_xor(i1v[rt][reg], mask); \
        float om2 = __shfl_xor(m2v[rt][reg], mask); \
        if (om1 < m1v[rt][reg]) { \
            m2v[rt][reg] = fminf(m1v[rt][reg], om2); m1v[rt][reg] = om1; i1v[rt][reg] = oi; \
        } else if (om1 > m1v[rt][reg]) { \
            m2v[rt][reg] = fminf(m2v[rt][reg], om1); \
        } else { \
            if (oi < i1v[rt][reg]) i1v[rt][reg] = oi; \
            m2v[rt][reg] = m1v[rt][reg]; } }
#define RED4(rt, reg) RED(rt, reg, 1) RED(rt, reg, 2) RED(rt, reg, 4) RED(rt, reg, 8)
    RED4(0, 0) RED4(0, 1) RED4(0, 2) RED4(0, 3)
    RED4(1, 0) RED4(1, 1) RED4(1, 2) RED4(1, 3)

    if (r16 == 0) {
        int g = lane >> 4;
#define WOUT(rt, reg) { \
        int row = rowbase + (rt) * 16 + 4 * g + (reg); \
        out[OUT_CODES + row] = (float)i1v[rt][reg]; \
        codes_i[row] = i1v[rt][reg]; \
        if (m2v[rt][reg] - m1v[rt][reg] < THR) { \
            int pos = atomicAdd(flagC, 1); \
            if (pos < FLAG_CAP) flagR[pos] = row; } }
        WOUT(0, 0) WOUT(0, 1) WOUT(0, 2) WOUT(0, 3)
        WOUT(1, 0) WOUT(1, 1) WOUT(1, 2) WOUT(1, 3)
    }
}

// ---- rescue: bit-exact np-f32 chain on flagged rows (one wave per row) ----
__global__ __launch_bounds__(64) void k_rescue(
        const float* __restrict__ ze, const float* __restrict__ emb,
        const float* __restrict__ csum, float* __restrict__ out,
        int* __restrict__ codes_i, const int* __restrict__ flagC,
        const int* __restrict__ flagR) {
    __shared__ float x2s[DIM];
    int nf = *flagC;
    if (nf > FLAG_CAP) nf = FLAG_CAP;
    int lane = threadIdx.x;
    for (int i = blockIdx.x; i < nf; i += gridDim.x) {
        int row = flagR[i];
        __syncthreads();
        float v = ze[(size_t)row * DIM + lane];
        x2s[lane] = __fadd_rn(v, v);
        __syncthreads();
        // A = 0.25 * numpy-pairwise((2x)^2), bit-exact (broadcast LDS reads)
        float r[8];
#pragma unroll
        for (int j = 0; j < 8; ++j) r[j] = __fmul_rn(x2s[j], x2s[j]);
#pragma unroll
        for (int b = 1; b < 8; ++b) {
#pragma unroll
            for (int j = 0; j < 8; ++j)
                r[j] = __fadd_rn(r[j], __fmul_rn(x2s[8 * b + j], x2s[8 * b + j]));
        }
        float A = __fmul_rn(0.25f,
            __fadd_rn(__fadd_rn(__fadd_rn(r[0], r[1]), __fadd_rn(r[2], r[3])),
                      __fadd_rn(__fadd_rn(r[4], r[5]), __fadd_rn(r[6], r[7]))));
        float m1 = 3.4e38f;
        int i1 = 0x7fffffff;
#pragma unroll
        for (int kk = 0; kk < 8; ++kk) {          // ascending k within lane
            int k = lane * 8 + kk;
            const float* e = emb + (size_t)k * DIM;
            float a = 0.f;
#pragma unroll
            for (int d = 0; d < DIM; ++d) a = __builtin_fmaf(x2s[d], e[d], a);
            float t = __fadd_rn(__fsub_rn(A, a), csum[k]);
            if (t < m1) { m1 = t; i1 = k; }       // strict < -> first occurrence in-lane
        }
        for (int off = 32; off; off >>= 1) {      // min with lowest-index tie-break
            float ov = __shfl_xor(m1, off);
            int oi = __shfl_xor(i1, off);
            if (ov < m1 || (ov == m1 && oi < i1)) { m1 = ov; i1 = oi; }
        }
        if (lane == 0) {
            out[OUT_CODES + row] = (float)i1;
            codes_i[row] = i1;
        }
    }
}

// ---- apply: z_q + loss + LDS histogram -> counts ----
__global__ __launch_bounds__(256) void k_apply(
        const float* __restrict__ ze, const float* __restrict__ emb,
        const int* __restrict__ codes_i, float* __restrict__ out,
        int* __restrict__ counts, double* __restrict__ lossAcc) {
    __shared__ int h[NCODE];
    __shared__ double ls[4];
    int t = threadIdx.x;
    for (int i = t; i < NCODE; i += 256) h[i] = 0;
    __syncthreads();
    int row = blockIdx.x * 256 + t;
    int code = codes_i[row];
    atomicAdd(&h[code], 1);
    const float* x = ze + (size_t)row * DIM;
    const float* e = emb + (size_t)code * DIM;
    float* zq = out + OUT_ZQ + (size_t)row * DIM;
    double lsum = 0.0;
#pragma unroll
    for (int d = 0; d < DIM; d += 4) {
        float4 xv = *reinterpret_cast<const float4*>(x + d);
        float4 ev = *reinterpret_cast<const float4*>(e + d);
        float ta = __fsub_rn(ev.x, xv.x);
        float tb = __fsub_rn(ev.y, xv.y);
        float tc = __fsub_rn(ev.z, xv.z);
        float td = __fsub_rn(ev.w, xv.w);
        float4 o;
        o.x = __fadd_rn(xv.x, ta);
        o.y = __fadd_rn(xv.y, tb);
        o.z = __fadd_rn(xv.z, tc);
        o.w = __fadd_rn(xv.w, td);
        *reinterpret_cast<float4*>(zq + d) = o;
        lsum += (double)ta * ta + (double)tb * tb + (double)tc * tc + (double)td * td;
    }
    for (int off = 32; off; off >>= 1) lsum += __shfl_down(lsum, off);
    int wid = t >> 6;
    if ((t & 63) == 0) ls[wid] = lsum;
    __syncthreads();
    if (t == 0) atomicAdd(lossAcc, (ls[0] + ls[1]) + (ls[2] + ls[3]));
    for (int k = t; k < NCODE; k += 256) {
        int cc = h[k];
        if (cc) atomicAdd(&counts[k], cc);
    }
}

// ---- one block: exclusive scan of counts -> offsets/cursor; new_ecs + n ----
__global__ __launch_bounds__(512) void k_scan(
        const int* __restrict__ counts, int* __restrict__ offsets, int* __restrict__ cursor,
        const float* __restrict__ ecs_in, float* __restrict__ out, float* __restrict__ n_out) {
    __shared__ int sa[NCODE], sb[NCODE];
    __shared__ float red[NCODE];
    int k = threadIdx.x;
    int c = counts[k];
    sa[k] = c;
    float v = __fadd_rn(__fmul_rn(ecs_in[k], DECAY_C), __fmul_rn((float)c, OMD_C));
    out[OUT_ECS + k] = v;
    red[k] = v;
    __syncthreads();
    int* src = sa;
    int* dst = sb;
    for (int off = 1; off < NCODE; off <<= 1) {
        dst[k] = (k >= off) ? src[k - off] + src[k] : src[k];
        __syncthreads();
        int* tp = src; src = dst; dst = tp;
    }
    offsets[k] = src[k] - c;
    cursor[k]  = src[k] - c;
    for (int s = NCODE / 2; s > 0; s >>= 1) {
        if (k < s) red[k] += red[k + s];
        __syncthreads();
    }
    if (k == 0) n_out[0] = red[0];
}

// ---- scatter rows into code buckets ----
__global__ __launch_bounds__(256) void k_scatter(
        const int* __restrict__ codes_i, int* __restrict__ cursor, int* __restrict__ bucket) {
    int row = blockIdx.x * 256 + threadIdx.x;
    int c = codes_i[row];
    int pos = atomicAdd(&cursor[c], 1);
    bucket[pos] = row;
}

// ---- per-code segmented sum, 4 blocks per code -> dw4 partials (no atomics) ----
__global__ __launch_bounds__(256) void k_dw(
        const float* __restrict__ ze, const int* __restrict__ bucket,
        const int* __restrict__ offsets, const int* __restrict__ counts,
        float* __restrict__ dw4) {
    __shared__ float p[4][DIM];
    int k = blockIdx.x >> 2;
    int q = blockIdx.x & 3;
    int w = threadIdx.x >> 6;
    int d = threadIdx.x & 63;
    int s = offsets[k];
    int n = counts[k];
    float acc0 = 0.f, acc1 = 0.f;
    int i = q + 4 * w;
    for (; i + 16 < n; i += 32) {
        int ra = bucket[s + i];
        int rb = bucket[s + i + 16];
        acc0 += ze[(size_t)ra * DIM + d];
        acc1 += ze[(size_t)rb * DIM + d];
    }
    if (i < n) acc0 += ze[(size_t)bucket[s + i] * DIM + d];
    p[w][d] = acc0 + acc1;
    __syncthreads();
    if (w == 0) dw4[((size_t)q * NCODE + k) * DIM + d] = (p[0][d] + p[1][d]) + (p[2][d] + p[3][d]);
}

// ---- new_ema_w, new_emb, loss ----
__global__ __launch_bounds__(256) void k_final(
        const float* __restrict__ ema_w, const float* __restrict__ dw4,
        const float* __restrict__ n_ptr, const double* __restrict__ lossAcc,
        float* __restrict__ out) {
    int i = blockIdx.x * blockDim.x + threadIdx.x;
    if (i >= NCODE * DIM) return;
    int k = i >> 6;
    float dsum = __fadd_rn(__fadd_rn(dw4[i], dw4[i + NCODE * DIM]),
                           __fadd_rn(dw4[i + 2 * NCODE * DIM], dw4[i + 3 * NCODE * DIM]));
    float w = __fadd_rn(__fmul_rn(ema_w[i], DECAY_C), __fmul_rn(dsum, OMD_C));
    out[OUT_EMAW + i] = w;
    float n = n_ptr[0];
    float necs = out[OUT_ECS + k];
    float cs = (necs + EPS_C) / (n + (float)NCODE * EPS_C) * n;
    out[OUT_EMB + i] = w / (cs + EPS_C);
    if (i == 0) out[OUT_LOSS] = (float)(0.1 * (lossAcc[0] / (double)((size_t)NROWS * DIM)));
}

extern "C" void kernel_launch(void* const* d_in, const int* in_sizes, int n_in,
                              void* d_out, int out_size, void* d_ws, size_t ws_size,
                              hipStream_t stream) {
    const float* ze   = (const float*)d_in[0];
    const float* emb  = (const float*)d_in[1];
    const float* ecs  = (const float*)d_in[2];
    const float* emaw = (const float*)d_in[3];
    float* out = (float*)d_out;
    char* ws = (char*)d_ws;
    double* lossAcc = (double*)(ws + WS_LOSS);
    float*  n_out   = (float*)(ws + WS_N);
    int*    flagC   = (int*)(ws + WS_FLAGC);
    int*    counts  = (int*)(ws + WS_COUNTS);
    int*    offsets = (int*)(ws + WS_OFFSETS);
    int*    cursor  = (int*)(ws + WS_CURSOR);
    float*  csum    = (float*)(ws + WS_CSUM);
    unsigned short* ehi = (unsigned short*)(ws + WS_EHI);
    unsigned short* elo = (unsigned short*)(ws + WS_ELO);
    int*    codes_i = (int*)(ws + WS_CODESI);
    float*  dw4     = (float*)(ws + WS_DW4);     // aliases codes_i (k_dw after k_scatter)
    int*    bucket  = (int*)(ws + WS_BUCKET);
    int*    flagR   = (int*)(ws + WS_FLAGR);     // aliases bucket (dead before k_scatter)

    hipMemsetAsync(d_ws, 0, WS_ZERO_BYTES, stream);
    hipLaunchKernelGGL(k_csum, dim3(2), dim3(256), 0, stream, emb, csum);
    hipLaunchKernelGGL(k_split, dim3(NCODE * DIM / 256), dim3(256), 0, stream, emb, ehi, elo);
    hipLaunchKernelGGL(k_mfma, dim3(NROWS / 128), dim3(256), 0, stream,
                       ze, ehi, elo, csum, out, codes_i, flagC, flagR);
    hipLaunchKernelGGL(k_rescue, dim3(1024), dim3(64), 0, stream,
                       ze, emb, csum, out, codes_i, flagC, flagR);
    hipLaunchKernelGGL(k_apply, dim3(NROWS / 256), dim3(256), 0, stream,
                       ze, emb, codes_i, out, counts, lossAcc);
    hipLaunchKernelGGL(k_scan, dim3(1), dim3(512), 0, stream,
                       counts, offsets, cursor, ecs, out, n_out);
    hipLaunchKernelGGL(k_scatter, dim3(NROWS / 256), dim3(256), 0, stream,
                       codes_i, cursor, bucket);
    hipLaunchKernelGGL(k_dw, dim3(NCODE * 4), dim3(256), 0, stream,
                       ze, bucket, offsets, counts, dw4);
    hipLaunchKernelGGL(k_final, dim3(NCODE * DIM / 256), dim3(256), 0, stream,
                       emaw, dw4, n_out, lossAcc, out);
}